// Round 1
// baseline (378.452 us; speedup 1.0000x reference)
//
#include <hip/hip_runtime.h>
#include <cstdint>

// LSTM cell: B=8192, DIM_IN=1024, DIM_OUT=1024, d=2048
// gates = [X|H][8192,2048] @ W[2048,4096] + b ; epilogue fused into GEMM.
// Strategy: cast to bf16, MFMA 16x16x32, m97-style 128x128 tile / BK=32,
// global_load_lds width=16 staging. W pre-permuted to B^T (n-major, k-contig)
// with gate-interleaved column order: n' = nb*128 + g*32 + jm  (j = nb*32+jm).

#define B_ROWS 8192
#define DK 2048
#define DOUT 1024
#define TM 128
#define TN 128
#define BK 32

typedef __bf16 bf16x8 __attribute__((ext_vector_type(8)));
typedef __bf16 bf16x4 __attribute__((ext_vector_type(4)));
typedef float f32x4 __attribute__((ext_vector_type(4)));

__device__ inline void load16_to_lds(const __bf16* gsrc, __bf16* ldst) {
    __builtin_amdgcn_global_load_lds(
        (const __attribute__((address_space(1))) void*)gsrc,
        (__attribute__((address_space(3))) void*)ldst,
        16, 0, 0);
}

__device__ inline float sigmoidf_fast(float x) {
    return 1.0f / (1.0f + __expf(-x));
}

// ---- prep 1: X = bf16(concat(x,h))  [8192][2048] row-major ----
__global__ __launch_bounds__(256) void prep_x(const float* __restrict__ x,
                                              const float* __restrict__ h,
                                              __bf16* __restrict__ X) {
    int id = blockIdx.x * 256 + threadIdx.x;   // 0 .. 8192*2048/4-1
    int b = id >> 9;          // 512 float4-groups per 2048-row
    int k = (id & 511) * 4;
    float4 v;
    if (k < 1024) v = *(const float4*)&x[(size_t)b * 1024 + k];
    else          v = *(const float4*)&h[(size_t)b * 1024 + (k - 1024)];
    bf16x4 o = { (__bf16)v.x, (__bf16)v.y, (__bf16)v.z, (__bf16)v.w };
    *(bf16x4*)&X[(size_t)b * 2048 + k] = o;
}

// ---- prep 2: Wt[n'][k] = bf16(W_g[k][j]),  g=(n'>>5)&3, j=(n'>>7)*32+(n'&31)
__global__ __launch_bounds__(256) void prep_w(const float* __restrict__ WI,
                                              const float* __restrict__ WF,
                                              const float* __restrict__ WG,
                                              const float* __restrict__ WO,
                                              __bf16* __restrict__ Wt) {
    int kb = blockIdx.x;       // 0..63  (k tiles of 32)
    int nb = blockIdx.y;       // 0..127 (n' tiles of 32)
    int g = nb & 3;
    int j0 = (nb >> 2) * 32;
    const float* W = (g == 0) ? WI : (g == 1) ? WF : (g == 2) ? WG : WO;
    __shared__ float t[32][33];
    int tx = threadIdx.x, ty0 = threadIdx.y;   // block (32,8)
    for (int yy = 0; yy < 32; yy += 8) {
        int k = kb * 32 + ty0 + yy;
        t[ty0 + yy][tx] = W[(size_t)k * 1024 + j0 + tx];
    }
    __syncthreads();
    for (int yy = 0; yy < 32; yy += 8) {
        int row = ty0 + yy;                    // n' within tile = j within group
        int np = nb * 32 + row;
        Wt[(size_t)np * 2048 + kb * 32 + tx] = (__bf16)t[tx][row];
    }
}

// ---- fused GEMM + LSTM epilogue ----
__global__ __launch_bounds__(256) void lstm_gemm(
    const __bf16* __restrict__ Xbf, const __bf16* __restrict__ Wt,
    const float* __restrict__ c,
    const float* __restrict__ bI, const float* __restrict__ bF,
    const float* __restrict__ bG, const float* __restrict__ bO,
    float* __restrict__ outH, float* __restrict__ outC)
{
    __shared__ __bf16 As[TM * BK];   // [row][k] 128x32
    __shared__ __bf16 Bs[TN * BK];   // [n'][k] 128x32

    const int t = threadIdx.x;
    const int lane = t & 63;
    const int wave = t >> 6;          // 4 waves, each 32 rows x 128 cols
    const int m0 = blockIdx.x * TM;   // 64
    const int nb = blockIdx.y;        // 32
    const int n0 = nb * TN;

    f32x4 acc[2][8];
#pragma unroll
    for (int i = 0; i < 2; ++i)
#pragma unroll
        for (int j = 0; j < 8; ++j) acc[i][j] = (f32x4){0.f, 0.f, 0.f, 0.f};

    // staging: chunk ci = iter*256 + t ; row = ci>>2 ; kc = ci&3 (8 bf16 each)
    const int r0 = t >> 2, kc0 = (t & 3) * 8;
    const int r1 = (256 + t) >> 2, kc1 = kc0;   // (256+t)&3 == t&3
    const __bf16* gA0 = Xbf + (size_t)(m0 + r0) * DK + kc0;
    const __bf16* gA1 = Xbf + (size_t)(m0 + r1) * DK + kc1;
    const __bf16* gB0 = Wt + (size_t)(n0 + r0) * DK + kc0;
    const __bf16* gB1 = Wt + (size_t)(n0 + r1) * DK + kc1;
    // wave-uniform LDS bases (HW adds lane*16 bytes)
    __bf16* lA0 = As + wave * 512;          // iter 0: bytes [wave*1024 ..]
    __bf16* lA1 = As + 2048 + wave * 512;   // iter 1: bytes [4096 + wave*1024]
    __bf16* lB0 = Bs + wave * 512;
    __bf16* lB1 = Bs + 2048 + wave * 512;

    const int lr = lane & 15;         // row-in-16 (A) / col-in-16 (B)
    const int kh = (lane >> 4) * 8;   // k sub-offset

    for (int kk = 0; kk < DK / BK; ++kk) {
        load16_to_lds(gA0, lA0);
        load16_to_lds(gA1, lA1);
        load16_to_lds(gB0, lB0);
        load16_to_lds(gB1, lB1);
        gA0 += BK; gA1 += BK; gB0 += BK; gB1 += BK;
        __syncthreads();   // drains vmcnt before barrier

        bf16x8 a0 = *(const bf16x8*)&As[(wave * 32 + lr) * BK + kh];
        bf16x8 a1 = *(const bf16x8*)&As[(wave * 32 + 16 + lr) * BK + kh];
        bf16x8 bb[8];
#pragma unroll
        for (int j = 0; j < 8; ++j)
            bb[j] = *(const bf16x8*)&Bs[(j * 16 + lr) * BK + kh];
#pragma unroll
        for (int j = 0; j < 8; ++j) {
            acc[0][j] = __builtin_amdgcn_mfma_f32_16x16x32_bf16(a0, bb[j], acc[0][j], 0, 0, 0);
            acc[1][j] = __builtin_amdgcn_mfma_f32_16x16x32_bf16(a1, bb[j], acc[1][j], 0, 0, 0);
        }
        __syncthreads();
    }

    // epilogue: C/D layout col=lane&15, row=(lane>>4)*4+reg
    const int col = lane & 15;
    const int rbase = m0 + wave * 32 + (lane >> 4) * 4;
#pragma unroll
    for (int i = 0; i < 2; ++i) {
#pragma unroll
        for (int p = 0; p < 2; ++p) {
            int j = nb * 32 + p * 16 + col;   // original gate column
            float biI = bI[j], biF = bF[j], biG = bG[j], biO = bO[j];
#pragma unroll
            for (int r = 0; r < 4; ++r) {
                int row = rbase + i * 16 + r;
                float vI = acc[i][0 + p][r] + biI;
                float vF = acc[i][2 + p][r] + biF;
                float vG = acc[i][4 + p][r] + biG;
                float vO = acc[i][6 + p][r] + biO;
                float I = sigmoidf_fast(vI);
                float F = sigmoidf_fast(vF);
                float G = tanhf(vG);
                float O = sigmoidf_fast(vO);
                size_t idx = (size_t)row * DOUT + j;
                float Cn = F * c[idx] + I * G;
                outH[idx] = O * tanhf(Cn);
                outC[idx] = Cn;
            }
        }
    }
}

extern "C" void kernel_launch(void* const* d_in, const int* in_sizes, int n_in,
                              void* d_out, int out_size, void* d_ws, size_t ws_size,
                              hipStream_t stream) {
    const float* x  = (const float*)d_in[0];
    const float* h  = (const float*)d_in[1];
    const float* c  = (const float*)d_in[2];
    const float* WI = (const float*)d_in[3];
    const float* bI = (const float*)d_in[4];
    const float* WF = (const float*)d_in[5];
    const float* bF = (const float*)d_in[6];
    const float* WG = (const float*)d_in[7];
    const float* bG = (const float*)d_in[8];
    const float* WO = (const float*)d_in[9];
    const float* bO = (const float*)d_in[10];

    __bf16* Xbf = (__bf16*)d_ws;                                   // 32 MB
    __bf16* Wt  = (__bf16*)((char*)d_ws + (size_t)B_ROWS * DK * 2); // 16 MB
    float* outH = (float*)d_out;
    float* outC = outH + (size_t)B_ROWS * DOUT;

    prep_x<<<(B_ROWS * DK / 4) / 256, 256, 0, stream>>>(x, h, Xbf);
    prep_w<<<dim3(DK / 32, 4 * DOUT / 32), dim3(32, 8), 0, stream>>>(WI, WF, WG, WO, Wt);
    lstm_gemm<<<dim3(B_ROWS / TM, 4 * DOUT / TN), 256, 0, stream>>>(
        Xbf, Wt, c, bI, bF, bG, bO, outH, outC);
}

// Round 2
// 357.670 us; speedup vs baseline: 1.0581x; 1.0581x over previous
//
#include <hip/hip_runtime.h>
#include <cstdint>

// LSTM cell: B=8192, DIM_IN=1024, DIM_OUT=1024, d=2048
// gates = [X|H][8192,2048] @ W[2048,4096] + b ; epilogue fused into GEMM.
// R1: 64x64 wave tiles (8 ds_read_b128 / 16 MFMA), fast exp2/rcp activations.
// W pre-permuted: n'' = jhi*64 + g*16 + jlo where j = jhi*16 + jlo, so each
// wave's 64 n''-columns = 16 j-columns x all 4 gates (in-register epilogue).

#define B_ROWS 8192
#define DK 2048
#define DOUT 1024
#define TM 128
#define TN 128
#define BK 32

typedef __bf16 bf16x8 __attribute__((ext_vector_type(8)));
typedef __bf16 bf16x4 __attribute__((ext_vector_type(4)));
typedef float f32x4 __attribute__((ext_vector_type(4)));

__device__ inline void load16_to_lds(const __bf16* gsrc, __bf16* ldst) {
    __builtin_amdgcn_global_load_lds(
        (const __attribute__((address_space(1))) void*)gsrc,
        (__attribute__((address_space(3))) void*)ldst,
        16, 0, 0);
}

// sigmoid(x) = 1/(1+2^(-x*log2e)); tanh(x) = 1 - 2/(1+2^(2x*log2e))
__device__ inline float fast_sigmoid(float x) {
    return __builtin_amdgcn_rcpf(1.0f + __builtin_amdgcn_exp2f(-1.442695041f * x));
}
__device__ inline float fast_tanh(float x) {
    return 1.0f - 2.0f * __builtin_amdgcn_rcpf(1.0f + __builtin_amdgcn_exp2f(2.885390082f * x));
}

// ---- prep 1: X = bf16(concat(x,h))  [8192][2048] row-major ----
__global__ __launch_bounds__(256) void prep_x(const float* __restrict__ x,
                                              const float* __restrict__ h,
                                              __bf16* __restrict__ X) {
    int id = blockIdx.x * 256 + threadIdx.x;
    int b = id >> 9;
    int k = (id & 511) * 4;
    float4 v;
    if (k < 1024) v = *(const float4*)&x[(size_t)b * 1024 + k];
    else          v = *(const float4*)&h[(size_t)b * 1024 + (k - 1024)];
    bf16x4 o = { (__bf16)v.x, (__bf16)v.y, (__bf16)v.z, (__bf16)v.w };
    *(bf16x4*)&X[(size_t)b * 2048 + k] = o;
}

// ---- prep 2: Wt[n''][k] = bf16(W_g[k][j]); n'' = (j>>4)*64 + g*16 + (j&15)
__global__ __launch_bounds__(256) void prep_w(const float* __restrict__ WI,
                                              const float* __restrict__ WF,
                                              const float* __restrict__ WG,
                                              const float* __restrict__ WO,
                                              __bf16* __restrict__ Wt) {
    int kb = blockIdx.x;       // 0..63  (k tiles of 32)
    int jb = blockIdx.y;       // 0..31  (j tiles of 32)
    int j0 = jb * 32;
    __shared__ float t[32][33];
    int tx = threadIdx.x, ty = threadIdx.y;   // block (32,8)
    const float* Ws[4] = {WI, WF, WG, WO};
#pragma unroll
    for (int g = 0; g < 4; ++g) {
        const float* W = Ws[g];
#pragma unroll
        for (int yy = 0; yy < 32; yy += 8) {
            int k = kb * 32 + ty + yy;
            t[ty + yy][tx] = W[(size_t)k * 1024 + j0 + tx];
        }
        __syncthreads();
#pragma unroll
        for (int yy = 0; yy < 32; yy += 8) {
            int r = ty + yy;                  // 0..31: jlo = r&15, jhi-sub = r>>4
            int npp = (jb * 2 + (r >> 4)) * 64 + g * 16 + (r & 15);
            Wt[(size_t)npp * 2048 + kb * 32 + tx] = (__bf16)t[tx][r];
        }
        __syncthreads();
    }
}

// ---- fused GEMM + LSTM epilogue ----
__global__ __launch_bounds__(256) void lstm_gemm(
    const __bf16* __restrict__ Xbf, const __bf16* __restrict__ Wt,
    const float* __restrict__ c,
    const float* __restrict__ bI, const float* __restrict__ bF,
    const float* __restrict__ bG, const float* __restrict__ bO,
    float* __restrict__ outH, float* __restrict__ outC)
{
    __shared__ __bf16 As[TM * BK];   // [row][k] 128x32
    __shared__ __bf16 Bs[TN * BK];   // [n''][k] 128x32

    const int t = threadIdx.x;
    const int lane = t & 63;
    const int wave = t >> 6;
    const int wm = wave >> 1;         // 2x2 waves of 64x64
    const int wn = wave & 1;
    const int m0 = blockIdx.x * TM;   // 64 blocks in M
    const int nb = blockIdx.y;        // 32 blocks in N
    const int n0 = nb * TN;

    f32x4 acc[4][4];
#pragma unroll
    for (int i = 0; i < 4; ++i)
#pragma unroll
        for (int j = 0; j < 4; ++j) acc[i][j] = (f32x4){0.f, 0.f, 0.f, 0.f};

    // staging: chunk ci = iter*256 + t ; row = ci>>2 ; kc = ci&3 (8 bf16 each)
    const int r0 = t >> 2, kc0 = (t & 3) * 8;
    const int r1 = 64 + r0;
    const __bf16* gA0 = Xbf + (size_t)(m0 + r0) * DK + kc0;
    const __bf16* gA1 = Xbf + (size_t)(m0 + r1) * DK + kc0;
    const __bf16* gB0 = Wt + (size_t)(n0 + r0) * DK + kc0;
    const __bf16* gB1 = Wt + (size_t)(n0 + r1) * DK + kc0;
    // wave-uniform LDS bases (HW adds lane*16 bytes)
    __bf16* lA0 = As + wave * 512;
    __bf16* lA1 = As + 2048 + wave * 512;
    __bf16* lB0 = Bs + wave * 512;
    __bf16* lB1 = Bs + 2048 + wave * 512;

    const int lr = lane & 15;
    const int kh = (lane >> 4) * 8;
    const int arow = wm * 64 + lr;
    const int brow = wn * 64 + lr;

    for (int kk = 0; kk < DK / BK; ++kk) {
        load16_to_lds(gA0, lA0);
        load16_to_lds(gA1, lA1);
        load16_to_lds(gB0, lB0);
        load16_to_lds(gB1, lB1);
        gA0 += BK; gA1 += BK; gB0 += BK; gB1 += BK;
        __syncthreads();

        bf16x8 a[4], b[4];
#pragma unroll
        for (int i = 0; i < 4; ++i)
            a[i] = *(const bf16x8*)&As[(arow + i * 16) * BK + kh];
#pragma unroll
        for (int j = 0; j < 4; ++j)
            b[j] = *(const bf16x8*)&Bs[(brow + j * 16) * BK + kh];
#pragma unroll
        for (int i = 0; i < 4; ++i)
#pragma unroll
            for (int j = 0; j < 4; ++j)
                acc[i][j] = __builtin_amdgcn_mfma_f32_16x16x32_bf16(a[i], b[j], acc[i][j], 0, 0, 0);
        __syncthreads();
    }

    // epilogue: C/D layout col=lane&15, row=(lane>>4)*4+reg; acc[i][g] = gate g
    const int col = lane & 15;
    const int j = (nb * 2 + wn) * 16 + col;     // original gate column
    const float biI = bI[j], biF = bF[j], biG = bG[j], biO = bO[j];
    const int rbase = m0 + wm * 64 + (lane >> 4) * 4;
#pragma unroll
    for (int i = 0; i < 4; ++i) {
#pragma unroll
        for (int r = 0; r < 4; ++r) {
            int row = rbase + i * 16 + r;
            float I = fast_sigmoid(acc[i][0][r] + biI);
            float F = fast_sigmoid(acc[i][1][r] + biF);
            float G = fast_tanh(acc[i][2][r] + biG);
            float O = fast_sigmoid(acc[i][3][r] + biO);
            size_t idx = (size_t)row * DOUT + j;
            float Cn = F * c[idx] + I * G;
            outH[idx] = O * fast_tanh(Cn);
            outC[idx] = Cn;
        }
    }
}

extern "C" void kernel_launch(void* const* d_in, const int* in_sizes, int n_in,
                              void* d_out, int out_size, void* d_ws, size_t ws_size,
                              hipStream_t stream) {
    const float* x  = (const float*)d_in[0];
    const float* h  = (const float*)d_in[1];
    const float* c  = (const float*)d_in[2];
    const float* WI = (const float*)d_in[3];
    const float* bI = (const float*)d_in[4];
    const float* WF = (const float*)d_in[5];
    const float* bF = (const float*)d_in[6];
    const float* WG = (const float*)d_in[7];
    const float* bG = (const float*)d_in[8];
    const float* WO = (const float*)d_in[9];
    const float* bO = (const float*)d_in[10];

    __bf16* Xbf = (__bf16*)d_ws;                                    // 32 MB
    __bf16* Wt  = (__bf16*)((char*)d_ws + (size_t)B_ROWS * DK * 2); // 16 MB
    float* outH = (float*)d_out;
    float* outC = outH + (size_t)B_ROWS * DOUT;

    prep_x<<<(B_ROWS * DK / 4) / 256, 256, 0, stream>>>(x, h, Xbf);
    prep_w<<<dim3(DK / 32, DOUT / 32), dim3(32, 8), 0, stream>>>(WI, WF, WG, WO, Wt);
    lstm_gemm<<<dim3(B_ROWS / TM, 4 * DOUT / TN), 256, 0, stream>>>(
        Xbf, Wt, c, bI, bF, bG, bO, outH, outC);
}